// Round 7
// baseline (189.398 us; speedup 1.0000x reference)
//
#include <hip/hip_runtime.h>
#include <hip/hip_cooperative_groups.h>

typedef _Float16 f16;
typedef f16 f16x8 __attribute__((ext_vector_type(8)));
typedef float f32x4 __attribute__((ext_vector_type(4)));

#define MFMA(A,B,C) __builtin_amdgcn_mfma_f32_16x16x32_f16(A,B,C,0,0,0)

// ws byte offsets (3.4 MB total -> L2-resident)
#define PTRUNK 0u          // 5 mats * 8ks * 16ct * 64lane * 16B = 640 KB
#define PHEAD  655360u     // 16bly * 8ks * 21ct * 64lane * 16B = 2.625 MB

// dynamic LDS layout (80384 B total)
//   prep phase: two staging tiles f16[16][264] at [0, 8448) and [8448, 16896)
//   [0      .. 16896)  Ah1   f16[32][264]
//   [16896  .. 33792)  Al1
//   [33792  .. 50688)  Ah0   (trunk)        | overlaid: prm f32[128][89] (head)
//   [50688  .. 67584)  Al0   (trunk)        |           = [33792 .. 79360)
//   [79360  .. 80384)  ladp  f32[8][32]
#define SMEM_BYTES 80384

__device__ __forceinline__ void fsplit(float v, f16& hi, f16& lo) {
    hi = (f16)v;
    lo = (f16)(v - (float)hi);
}

// ---------------------------------------------------------------------------
// mega v4 (cooperative): phase 0 packs masked fp16 weights into MFMA fragment
// order (2 staging units per WG, 416 total), grid.sync, then trunk (5 masked
// GEMM layers, balanced wave split ct {w,15-w}) + barrier-free head
// (bly {w,15-w}), identical to round-6 body.
// Fragment elem e of lane l: k = (l>>4)*8+e, col = ct*16+(l&15).
// Head K ROTATED: pos 0 -> j=255, pos p -> j=p-1 (prefix K-sets).
// ---------------------------------------------------------------------------
__global__ __launch_bounds__(512, 2) void mega_kernel(
    const float* __restrict__ x, unsigned char* __restrict__ wsb,
    const float* __restrict__ W0, const float* __restrict__ b0,
    const float* __restrict__ Wb, const float* __restrict__ bb,
    const float* __restrict__ Wf, const float* __restrict__ bfp,
    float* __restrict__ out, float* __restrict__ lad)
{
    extern __shared__ unsigned char smem[];
    f16 (*Ah1)[264] = (f16(*)[264])(smem);
    f16 (*Al1)[264] = (f16(*)[264])(smem + 16896);
    f16 (*Ah0)[264] = (f16(*)[264])(smem + 33792);
    f16 (*Al0)[264] = (f16(*)[264])(smem + 50688);
    float* prm      = (float*)(smem + 33792);    // [128][89], head phase only
    float* ladp     = (float*)(smem + 79360);    // [8][32]

    const int t = threadIdx.x, lane = t & 63;
    const int wu = __builtin_amdgcn_readfirstlane(t >> 6);   // wave id 0..7
    const int li = lane & 15, lg = lane >> 4;
    const int r0 = blockIdx.x * 32;

    // ================= phase 0: prep (2 units per WG) =================
    {
        f16 (*sm)[264] = (f16(*)[264])(smem + (t >> 8) * 8448);
        const int tl = t & 255;
        const int cr = tl >> 4, kc = tl & 15;
        const int u  = blockIdx.x * 2 + (t >> 8);   // staging unit 0..511

        if (u < 80) {                        // trunk: mat = u>>4, ct = u&15
            const int mat = u >> 4, ct = u & 15;
            const int c = ct * 16 + cr;
            const int cd = c % 255;
            const float* src = ((mat == 0) ? W0 : (Wb + (mat - 1) * 65536)) + c * 256;
            #pragma unroll
            for (int uu = 0; uu < 4; ++uu) {
                const int k = kc * 16 + uu * 4;
                float4 v = *(const float4*)(src + k);
                float vv[4] = {v.x, v.y, v.z, v.w};
                #pragma unroll
                for (int e = 0; e < 4; ++e) {
                    int kk = k + e;
                    int kd = (mat == 0) ? kk : (kk % 255);
                    sm[cr][kk] = (cd >= kd) ? (f16)vv[e] : (f16)0.f;
                }
            }
        } else if (u < 416) {                // head: hb = u-80 -> (bly, ct)
            const int hb = u - 80;
            const int bly = hb / 21, ct = hb - bly * 21;
            const int cl = ct * 16 + cr;
            const int fw = cl / 21;
            const int f  = bly * 16 + fw;
            const int m  = cl - fw * 21;
            const float* src = Wf + (f * 21 + m) * 256;
            #pragma unroll
            for (int uu = 0; uu < 4; ++uu) {
                const int k = kc * 16 + uu * 4;
                float4 v = *(const float4*)(src + k);
                float vv[4] = {v.x, v.y, v.z, v.w};
                #pragma unroll
                for (int e = 0; e < 4; ++e) {
                    int kk = k + e;
                    int jd = kk % 255;
                    sm[cr][(kk + 1) & 255] = (f > jd) ? (f16)vv[e] : (f16)0.f;
                }
            }
        }
        __syncthreads();
        if (u < 416) {
            const int ks = tl >> 5, ln = tl & 31;
            #pragma unroll
            for (int rep = 0; rep < 2; ++rep) {
                const int L  = ln + rep * 32;
                const int l2 = L & 15, g2 = L >> 4;
                f16x8 v = *(const f16x8*)&sm[l2][ks * 32 + g2 * 8];
                if (u < 80) {
                    const int mat = u >> 4, ct = u & 15;
                    ((f16x8*)(wsb + PTRUNK))[(mat * 128 + ks * 16 + ct) * 64 + L] = v;
                } else {
                    const int hb = u - 80;
                    const int bly = hb / 21, ct = hb - bly * 21;
                    ((f16x8*)(wsb + PHEAD))[((bly * 8 + ks) * 21 + ct) * 64 + L] = v;
                }
            }
        }
        cooperative_groups::this_grid().sync();
    }

    // ================= phase 1: trunk + head =================

    // ---- stage x hi/lo into buffer 0 ----
    {
        const int row = t >> 4, cb = (t & 15) * 16;
        const float* xr = x + (r0 + row) * 256 + cb;
        f16 hi[16], lo[16];
        #pragma unroll
        for (int j = 0; j < 16; j += 4) {
            float4 v4 = *(const float4*)(xr + j);
            fsplit(v4.x, hi[j],     lo[j]);
            fsplit(v4.y, hi[j + 1], lo[j + 1]);
            fsplit(v4.z, hi[j + 2], lo[j + 2]);
            fsplit(v4.w, hi[j + 3], lo[j + 3]);
        }
        *(f16x8*)&Ah0[row][cb]     = *(f16x8*)&hi[0];
        *(f16x8*)&Ah0[row][cb + 8] = *(f16x8*)&hi[8];
        *(f16x8*)&Al0[row][cb]     = *(f16x8*)&lo[0];
        *(f16x8*)&Al0[row][cb + 8] = *(f16x8*)&lo[8];
    }
    __syncthreads();

    const f16x8* wt = (const f16x8*)(wsb + PTRUNK);
    const f16x8* wh = (const f16x8*)(wsb + PHEAD);

    const int ctA = wu, ctB = 15 - wu;
    const int nkA = (ctA >> 1) + 1;        // 1..4
    const int nkB = (ctB >> 1) + 1;        // 5..8

    f32x4 acc[2][2], h[2][2];

    auto gemm = [&](int mat, f16 (*Sh)[264], f16 (*Sl)[264],
                    const float* __restrict__ bias) {
        const int a7 = (mat > 0) ? 1 : 0;
        const int tB = nkB + ((a7 && nkB < 8) ? 1 : 0);
        const f16x8* wb = wt + mat * 8192;
        f16x8 bfA[9], bfB[9];
        #pragma unroll
        for (int s = 0; s < 9; ++s) {
            if (s < tB) {
                const int ks = (s < nkB) ? s : 7;
                bfB[s] = wb[(ks * 16 + ctB) * 64 + lane];
                if (ks < nkA || (a7 && ks == 7))
                    bfA[s] = wb[(ks * 16 + ctA) * 64 + lane];
            }
        }
        #pragma unroll
        for (int ci = 0; ci < 2; ++ci)
            #pragma unroll
            for (int rt = 0; rt < 2; ++rt)
                acc[ci][rt] = (f32x4){0.f, 0.f, 0.f, 0.f};
        #pragma unroll
        for (int s = 0; s < 9; ++s) {
            if (s < tB) {
                const int ks = (s < nkB) ? s : 7;
                const int ko = ks * 32 + lg * 8;
                f16x8 ah0 = *(const f16x8*)&Sh[li][ko];
                f16x8 al0 = *(const f16x8*)&Sl[li][ko];
                f16x8 ah1 = *(const f16x8*)&Sh[16 + li][ko];
                f16x8 al1 = *(const f16x8*)&Sl[16 + li][ko];
                acc[1][0] = MFMA(al0, bfB[s], acc[1][0]);
                acc[1][0] = MFMA(ah0, bfB[s], acc[1][0]);
                acc[1][1] = MFMA(al1, bfB[s], acc[1][1]);
                acc[1][1] = MFMA(ah1, bfB[s], acc[1][1]);
                if (ks < nkA || (a7 && ks == 7)) {
                    acc[0][0] = MFMA(al0, bfA[s], acc[0][0]);
                    acc[0][0] = MFMA(ah0, bfA[s], acc[0][0]);
                    acc[0][1] = MFMA(al1, bfA[s], acc[0][1]);
                    acc[0][1] = MFMA(ah1, bfA[s], acc[0][1]);
                }
            }
        }
        const float bvA = bias[ctA * 16 + li];
        const float bvB = bias[ctB * 16 + li];
        #pragma unroll
        for (int rt = 0; rt < 2; ++rt)
            #pragma unroll
            for (int q = 0; q < 4; ++q) {
                acc[0][rt][q] += bvA;
                acc[1][rt][q] += bvB;
            }
    };

    auto store_act = [&](f16 (*Dh)[264], f16 (*Dl)[264], f32x4 (&s)[2][2],
                         bool relu, bool rot) {
        #pragma unroll
        for (int ci = 0; ci < 2; ++ci) {
            const int c  = (ci ? ctB : ctA) * 16 + li;
            const int cc = rot ? ((c + 1) & 255) : c;
            #pragma unroll
            for (int rt = 0; rt < 2; ++rt)
                #pragma unroll
                for (int q = 0; q < 4; ++q) {
                    float v = s[ci][rt][q];
                    if (relu) v = fmaxf(v, 0.f);
                    f16 hi, lo; fsplit(v, hi, lo);
                    Dh[rt * 16 + lg * 4 + q][cc] = hi;
                    Dl[rt * 16 + lg * 4 + q][cc] = lo;
                }
        }
    };

    // ---- trunk: 5 layers, 1 barrier each ----
    gemm(0, Ah0, Al0, b0);
    #pragma unroll
    for (int ci = 0; ci < 2; ++ci)
        #pragma unroll
        for (int rt = 0; rt < 2; ++rt) h[ci][rt] = acc[ci][rt];
    store_act(Ah1, Al1, acc, true, false);
    __syncthreads();

    gemm(1, Ah1, Al1, bb);
    store_act(Ah0, Al0, acc, true, false);
    __syncthreads();

    gemm(2, Ah0, Al0, bb + 256);
    #pragma unroll
    for (int ci = 0; ci < 2; ++ci)
        #pragma unroll
        for (int rt = 0; rt < 2; ++rt) h[ci][rt] += acc[ci][rt];
    store_act(Ah1, Al1, h, true, false);
    __syncthreads();

    gemm(3, Ah1, Al1, bb + 512);
    store_act(Ah0, Al0, acc, true, false);
    __syncthreads();

    gemm(4, Ah0, Al0, bb + 768);
    #pragma unroll
    for (int ci = 0; ci < 2; ++ci)
        #pragma unroll
        for (int rt = 0; rt < 2; ++rt) h[ci][rt] += acc[ci][rt];
    store_act(Ah1, Al1, h, false, true);     // final h: no relu, K-rotated
    __syncthreads();                          // buf0 now dead -> prm overlay

    // ---- head: wave-private blys {wu, 15-wu}, barrier-free ----
    float lr0 = 0.f, lr1 = 0.f;

    auto do_half = [&](const f32x4* hacc, int hp, float xv, int pass, int f0,
                       int fme, float& lr) {
        #pragma unroll
        for (int ci = 0; ci < 6; ++ci) {
            const int cl = (pass * 5 + ci) * 16 + li;
            const int fw = cl / 21;
            const int m  = cl - fw * 21;
            if (fw >= pass * 4 && fw < pass * 4 + 4) {
                const float bv = bfp[f0 * 21 + cl];
                #pragma unroll
                for (int q = 0; q < 4; ++q)
                    prm[(wu * 16 + lg * 4 + q) * 89 + (fw - pass * 4) * 22 + m] =
                        (hacc[ci][q] + bv) * 0.0625f;
            }
        }
        float p[21];
        #pragma unroll
        for (int m = 0; m < 21; ++m)
            p[m] = prm[(wu * 16 + li) * 89 + lg * 22 + m];

        float wmax = p[0];
        #pragma unroll
        for (int i = 1; i < 10; ++i) wmax = fmaxf(wmax, p[i]);
        float ew[10]; float wsum = 0.f;
        #pragma unroll
        for (int i = 0; i < 10; ++i) { ew[i] = __expf(p[i] - wmax); wsum += ew[i]; }
        const float winv = 1.0f / wsum;
        float wid[10];
        #pragma unroll
        for (int i = 0; i < 10; ++i) wid[i] = 1.0e-3f + 0.99f * ew[i] * winv;

        float hx[11];
        #pragma unroll
        for (int i = 0; i < 11; ++i) hx[i] = __expf(p[10 + i]);
        float area = 0.f;
        #pragma unroll
        for (int i = 0; i < 10; ++i) area += (hx[i] + hx[i + 1]) * wid[i];
        const float ainv = 2.0f / area;
        float hts[11];
        #pragma unroll
        for (int i = 0; i < 11; ++i) hts[i] = 1.0e-3f + 0.999f * hx[i] * ainv;

        float la = wid[0];
        float ca = 0.5f * (hts[0] + hts[1]) * wid[0];
        float loc = 0.f, ww = wid[0], lc = 0.f, hl = hts[0], hr = hts[1];
        #pragma unroll
        for (int i = 1; i < 10; ++i) {
            const bool sel = (xv >= la);
            loc = sel ? la : loc;
            ww  = sel ? wid[i] : ww;
            lc  = sel ? ca : lc;
            hl  = sel ? hts[i] : hl;
            hr  = sel ? hts[i + 1] : hr;
            la += wid[i];
            ca += 0.5f * (hts[i] + hts[i + 1]) * wid[i];
        }
        const float al2 = (xv - loc) / ww;
        const float dh  = hr - hl;
        float y = (0.5f * dh * ww * al2 + hl * ww) * al2 + lc;
        y = fminf(fmaxf(y, 0.f), 1.f);
        out[(r0 + hp * 16 + li) * 256 + fme] = y;
        lr += __logf(al2 * dh + hl);
    };

    #pragma unroll
    for (int ib = 0; ib < 2; ++ib) {
        const int bly = ib ? (15 - wu) : wu;
        const int nl  = (bly + 2) >> 1;          // 1..8, wave-uniform
        const int f0  = bly * 16;
        const int bly8 = bly * 8;

        #pragma unroll
        for (int pass = 0; pass < 4; ++pass) {
            const int p5  = pass * 5;
            const int fme = f0 + pass * 4 + lg;
            const float xv0 = x[(r0 + li) * 256 + fme];
            const float xv1 = x[(r0 + 16 + li) * 256 + fme];

            f32x4 pA[6], pB[6];
            #pragma unroll
            for (int ci = 0; ci < 6; ++ci) {
                pA[ci] = (f32x4){0.f, 0.f, 0.f, 0.f};
                pB[ci] = (f32x4){0.f, 0.f, 0.f, 0.f};
            }

            f16x8 c0[6], c1[6];
            #pragma unroll
            for (int ci = 0; ci < 6; ++ci)
                c0[ci] = wh[(bly8 * 21 + p5 + ci) * 64 + lane];

            __builtin_amdgcn_s_setprio(1);
            for (int s = 0; s < nl; s += 2) {
                const int s1 = (s + 1 < nl) ? s + 1 : 0;
                #pragma unroll
                for (int ci = 0; ci < 6; ++ci)
                    c1[ci] = wh[((bly8 + s1) * 21 + p5 + ci) * 64 + lane];
                {
                    const int ko = s * 32 + lg * 8;
                    f16x8 ah0 = *(const f16x8*)&Ah1[li][ko];
                    f16x8 al0 = *(const f16x8*)&Al1[li][ko];
                    f16x8 ah1 = *(const f16x8*)&Ah1[16 + li][ko];
                    f16x8 al1 = *(const f16x8*)&Al1[16 + li][ko];
                    #pragma unroll
                    for (int ci = 0; ci < 6; ++ci) {
                        pA[ci] = MFMA(al0, c0[ci], pA[ci]);
                        pA[ci] = MFMA(ah0, c0[ci], pA[ci]);
                        pB[ci] = MFMA(al1, c0[ci], pB[ci]);
                        pB[ci] = MFMA(ah1, c0[ci], pB[ci]);
                    }
                }
                const int s2 = (s + 2 < nl) ? s + 2 : 0;
                #pragma unroll
                for (int ci = 0; ci < 6; ++ci)
                    c0[ci] = wh[((bly8 + s2) * 21 + p5 + ci) * 64 + lane];
                if (s + 1 < nl) {
                    const int ko = s1 * 32 + lg * 8;
                    f16x8 ah0 = *(const f16x8*)&Ah1[li][ko];
                    f16x8 al0 = *(const f16x8*)&Al1[li][ko];
                    f16x8 ah1 = *(const f16x8*)&Ah1[16 + li][ko];
                    f16x8 al1 = *(const f16x8*)&Al1[16 + li][ko];
                    #pragma unroll
                    for (int ci = 0; ci < 6; ++ci) {
                        pA[ci] = MFMA(al0, c1[ci], pA[ci]);
                        pA[ci] = MFMA(ah0, c1[ci], pA[ci]);
                        pB[ci] = MFMA(al1, c1[ci], pB[ci]);
                        pB[ci] = MFMA(ah1, c1[ci], pB[ci]);
                    }
                }
            }
            __builtin_amdgcn_s_setprio(0);

            do_half(pA, 0, xv0, pass, f0, fme, lr0);
            do_half(pB, 1, xv1, pass, f0, fme, lr1);
        }
    }

    // ---- logabsdet: reduce over feature-slots (lg), then waves ----
    lr0 += __shfl_xor(lr0, 16); lr0 += __shfl_xor(lr0, 32);
    lr1 += __shfl_xor(lr1, 16); lr1 += __shfl_xor(lr1, 32);
    if (lane < 16) {
        ladp[wu * 32 + lane]      = lr0;
        ladp[wu * 32 + 16 + lane] = lr1;
    }
    __syncthreads();
    if (t < 32) {
        float s = 0.f;
        #pragma unroll
        for (int w2 = 0; w2 < 8; ++w2) s += ladp[w2 * 32 + t];
        lad[r0 + t] = s;
    }
}

// ---------------------------------------------------------------------------
extern "C" void kernel_launch(void* const* d_in, const int* in_sizes, int n_in,
                              void* d_out, int out_size, void* d_ws, size_t ws_size,
                              hipStream_t stream)
{
    const float* x  = (const float*)d_in[0];
    const float* W0 = (const float*)d_in[1];
    const float* b0 = (const float*)d_in[2];
    const float* Wb = (const float*)d_in[3];
    const float* bb = (const float*)d_in[4];
    const float* Wf = (const float*)d_in[5];
    const float* bf = (const float*)d_in[6];

    float* out = (float*)d_out;
    float* lad = out + 8192 * 256;
    unsigned char* wsb = (unsigned char*)d_ws;

    hipFuncSetAttribute(reinterpret_cast<const void*>(mega_kernel),
                        hipFuncAttributeMaxDynamicSharedMemorySize, SMEM_BYTES);

    void* args[] = {(void*)&x, (void*)&wsb, (void*)&W0, (void*)&b0,
                    (void*)&Wb, (void*)&bb, (void*)&Wf, (void*)&bf,
                    (void*)&out, (void*)&lad};
    hipLaunchCooperativeKernel(reinterpret_cast<void*>(mega_kernel),
                               dim3(256), dim3(512), args, SMEM_BYTES, stream);
}

// Round 8
// 137.760 us; speedup vs baseline: 1.3748x; 1.3748x over previous
//
#include <hip/hip_runtime.h>

typedef _Float16 f16;
typedef f16 f16x8 __attribute__((ext_vector_type(8)));
typedef float f32x4 __attribute__((ext_vector_type(4)));

#define MFMA(A,B,C) __builtin_amdgcn_mfma_f32_16x16x32_f16(A,B,C,0,0,0)

// ws byte offsets (3.4 MB total -> L2-resident)
#define PTRUNK 0u          // 5 mats * 8ks * 16ct * 64lane * 16B = 640 KB
#define PHEAD  655360u     // 16bly * 8ks * 21ct * 64lane * 16B = 2.625 MB

// dynamic LDS layout (62976 B -> 2 WGs/CU)
//   [0     .. 8448 )  Ah1  f16[16][264]
//   [8448  .. 16896)  Al1
//   [16896 .. 25344)  Ah0  (trunk)   | overlaid in head phase:
//   [25344 .. 33792)  Al0  (trunk)   |   prm f32[128][89] = [16896 .. 62464)
//   [62464 .. 62976)  ladp f32[8][16]
#define SMEM_BYTES 62976

__device__ __forceinline__ void fsplit(float v, f16& hi, f16& lo) {
    hi = (f16)v;
    lo = (f16)(v - (float)hi);
}

// ---------------------------------------------------------------------------
// prep: LDS-staged transpose into MFMA fragment order, fp16 (unchanged).
// Fragment elem e of lane l: k = (l>>4)*8+e, col = ct*16+(l&15).
// Head K ROTATED: pos 0 -> j=255, pos p -> j=p-1 (prefix K-sets).
// ---------------------------------------------------------------------------
__global__ __launch_bounds__(256) void prep_kernel(
    const float* __restrict__ W0, const float* __restrict__ Wb,
    const float* __restrict__ Wf, unsigned char* __restrict__ wsb)
{
    __shared__ f16 sm[16][264];
    const int b = blockIdx.x, t = threadIdx.x;
    const int cr = t >> 4, kc = t & 15;

    if (b < 80) {                            // trunk: mat = b>>4, ct = b&15
        const int mat = b >> 4, ct = b & 15;
        const int c = ct * 16 + cr;
        const int cd = c % 255;
        const float* src = ((mat == 0) ? W0 : (Wb + (mat - 1) * 65536)) + c * 256;
        #pragma unroll
        for (int u = 0; u < 4; ++u) {
            const int k = kc * 16 + u * 4;
            float4 v = *(const float4*)(src + k);
            float vv[4] = {v.x, v.y, v.z, v.w};
            #pragma unroll
            for (int e = 0; e < 4; ++e) {
                int kk = k + e;
                int kd = (mat == 0) ? kk : (kk % 255);
                sm[cr][kk] = (cd >= kd) ? (f16)vv[e] : (f16)0.f;
            }
        }
        __syncthreads();
        const int ks = t >> 5, ln = t & 31;
        #pragma unroll
        for (int rep = 0; rep < 2; ++rep) {
            const int L = ln + rep * 32;
            const int li = L & 15, lg = L >> 4;
            f16x8 v = *(const f16x8*)&sm[li][ks * 32 + lg * 8];
            ((f16x8*)(wsb + PTRUNK))[(mat * 128 + ks * 16 + ct) * 64 + L] = v;
        }
    } else {                                 // head: hb = b-80 -> (bly, ct)
        const int hb = b - 80;
        const int bly = hb / 21, ct = hb - bly * 21;
        const int cl = ct * 16 + cr;
        const int fw = cl / 21;
        const int f  = bly * 16 + fw;
        const int m  = cl - fw * 21;
        const float* src = Wf + (f * 21 + m) * 256;
        #pragma unroll
        for (int u = 0; u < 4; ++u) {
            const int k = kc * 16 + u * 4;
            float4 v = *(const float4*)(src + k);
            float vv[4] = {v.x, v.y, v.z, v.w};
            #pragma unroll
            for (int e = 0; e < 4; ++e) {
                int kk = k + e;
                int jd = kk % 255;
                sm[cr][(kk + 1) & 255] = (f > jd) ? (f16)vv[e] : (f16)0.f;
            }
        }
        __syncthreads();
        const int ks = t >> 5, ln = t & 31;
        #pragma unroll
        for (int rep = 0; rep < 2; ++rep) {
            const int L = ln + rep * 32;
            const int li = L & 15, lg = L >> 4;
            f16x8 v = *(const f16x8*)&sm[li][ks * 32 + lg * 8];
            ((f16x8*)(wsb + PHEAD))[((bly * 8 + ks) * 21 + ct) * 64 + L] = v;
        }
    }
}

// ---------------------------------------------------------------------------
// mega v5: 512 WGs x 512 thr, 16 rows/WG, 8 waves, 2 WGs/CU (4 waves/SIMD).
// Trunk: wave w owns ct {w, 15-w} (balanced Sum nks = 9), full-register B
// preload. Head: wave w owns bly {w, 15-w} (balanced Sum nl = 9),
// barrier-free, dbuf B prefetch, setprio, wave-private prm overlay.
// ---------------------------------------------------------------------------
__global__ __launch_bounds__(512, 4) void mega_kernel(
    const float* __restrict__ x, const unsigned char* __restrict__ wsb,
    const float* __restrict__ b0, const float* __restrict__ bb,
    const float* __restrict__ bfp, float* __restrict__ out,
    float* __restrict__ lad)
{
    extern __shared__ unsigned char smem[];
    f16 (*Ah1)[264] = (f16(*)[264])(smem);
    f16 (*Al1)[264] = (f16(*)[264])(smem + 8448);
    f16 (*Ah0)[264] = (f16(*)[264])(smem + 16896);
    f16 (*Al0)[264] = (f16(*)[264])(smem + 25344);
    float* prm      = (float*)(smem + 16896);    // [128][89], head phase only
    float* ladp     = (float*)(smem + 62464);    // [8][16]

    const int t = threadIdx.x, lane = t & 63;
    const int wu = __builtin_amdgcn_readfirstlane(t >> 6);   // wave id 0..7
    const int li = lane & 15, lg = lane >> 4;
    const int r0 = blockIdx.x * 16;

    // ---- stage x hi/lo into buffer 0: 16 rows x 256 cols, 8 cols/thread ----
    {
        const int row = t >> 5, cb = (t & 31) * 8;
        const float* xr = x + (r0 + row) * 256 + cb;
        float4 va = *(const float4*)(xr);
        float4 vb = *(const float4*)(xr + 4);
        float v[8] = {va.x, va.y, va.z, va.w, vb.x, vb.y, vb.z, vb.w};
        f16 hi[8], lo[8];
        #pragma unroll
        for (int j = 0; j < 8; ++j) fsplit(v[j], hi[j], lo[j]);
        *(f16x8*)&Ah0[row][cb] = *(f16x8*)hi;
        *(f16x8*)&Al0[row][cb] = *(f16x8*)lo;
    }
    __syncthreads();

    const f16x8* wt = (const f16x8*)(wsb + PTRUNK);
    const f16x8* wh = (const f16x8*)(wsb + PHEAD);

    const int ctA = wu, ctB = 15 - wu;
    const int nkA = (ctA >> 1) + 1;        // 1..4
    const int nkB = (ctB >> 1) + 1;        // 5..8

    f32x4 acc[2], h[2];

    auto gemm = [&](int mat, f16 (*Sh)[264], f16 (*Sl)[264],
                    const float* __restrict__ bias) {
        const int a7 = (mat > 0) ? 1 : 0;
        const int tB = nkB + ((a7 && nkB < 8) ? 1 : 0);
        const f16x8* wb = wt + mat * 8192;
        f16x8 bfA[9], bfB[9];
        #pragma unroll
        for (int s = 0; s < 9; ++s) {
            if (s < tB) {
                const int ks = (s < nkB) ? s : 7;
                bfB[s] = wb[(ks * 16 + ctB) * 64 + lane];
                if (ks < nkA || (a7 && ks == 7))
                    bfA[s] = wb[(ks * 16 + ctA) * 64 + lane];
            }
        }
        acc[0] = (f32x4){0.f, 0.f, 0.f, 0.f};
        acc[1] = (f32x4){0.f, 0.f, 0.f, 0.f};
        #pragma unroll
        for (int s = 0; s < 9; ++s) {
            if (s < tB) {
                const int ks = (s < nkB) ? s : 7;
                const int ko = ks * 32 + lg * 8;
                f16x8 ah = *(const f16x8*)&Sh[li][ko];
                f16x8 al = *(const f16x8*)&Sl[li][ko];
                acc[1] = MFMA(al, bfB[s], acc[1]);
                acc[1] = MFMA(ah, bfB[s], acc[1]);
                if (ks < nkA || (a7 && ks == 7)) {
                    acc[0] = MFMA(al, bfA[s], acc[0]);
                    acc[0] = MFMA(ah, bfA[s], acc[0]);
                }
            }
        }
        const float bvA = bias[ctA * 16 + li];
        const float bvB = bias[ctB * 16 + li];
        #pragma unroll
        for (int q = 0; q < 4; ++q) { acc[0][q] += bvA; acc[1][q] += bvB; }
    };

    auto store_act = [&](f16 (*Dh)[264], f16 (*Dl)[264], f32x4 (&s)[2],
                         bool relu, bool rot) {
        #pragma unroll
        for (int ci = 0; ci < 2; ++ci) {
            const int c  = (ci ? ctB : ctA) * 16 + li;
            const int cc = rot ? ((c + 1) & 255) : c;
            #pragma unroll
            for (int q = 0; q < 4; ++q) {
                float v = s[ci][q];
                if (relu) v = fmaxf(v, 0.f);
                f16 hi, lo; fsplit(v, hi, lo);
                Dh[lg * 4 + q][cc] = hi;
                Dl[lg * 4 + q][cc] = lo;
            }
        }
    };

    // ---- trunk: 5 layers, 1 barrier each ----
    gemm(0, Ah0, Al0, b0);
    h[0] = acc[0]; h[1] = acc[1];
    store_act(Ah1, Al1, acc, true, false);
    __syncthreads();

    gemm(1, Ah1, Al1, bb);
    store_act(Ah0, Al0, acc, true, false);
    __syncthreads();

    gemm(2, Ah0, Al0, bb + 256);
    h[0] += acc[0]; h[1] += acc[1];
    store_act(Ah1, Al1, h, true, false);
    __syncthreads();

    gemm(3, Ah1, Al1, bb + 512);
    store_act(Ah0, Al0, acc, true, false);
    __syncthreads();

    gemm(4, Ah0, Al0, bb + 768);
    h[0] += acc[0]; h[1] += acc[1];
    store_act(Ah1, Al1, h, false, true);     // final h: no relu, K-rotated
    __syncthreads();                          // buf0 dead -> prm overlay

    // ---- head: wave-private blys {wu, 15-wu}, barrier-free ----
    float lr0 = 0.f;

    auto do_half = [&](const f32x4* hacc, float xv, int pass, int f0,
                       int fme, float& lr) {
        #pragma unroll
        for (int ci = 0; ci < 6; ++ci) {
            const int cl = (pass * 5 + ci) * 16 + li;
            const int fw = cl / 21;
            const int m  = cl - fw * 21;
            if (fw >= pass * 4 && fw < pass * 4 + 4) {
                const float bv = bfp[f0 * 21 + cl];
                #pragma unroll
                for (int q = 0; q < 4; ++q)
                    prm[(wu * 16 + lg * 4 + q) * 89 + (fw - pass * 4) * 22 + m] =
                        (hacc[ci][q] + bv) * 0.0625f;
            }
        }
        float p[21];
        #pragma unroll
        for (int m = 0; m < 21; ++m)
            p[m] = prm[(wu * 16 + li) * 89 + lg * 22 + m];

        float wmax = p[0];
        #pragma unroll
        for (int i = 1; i < 10; ++i) wmax = fmaxf(wmax, p[i]);
        float ew[10]; float wsum = 0.f;
        #pragma unroll
        for (int i = 0; i < 10; ++i) { ew[i] = __expf(p[i] - wmax); wsum += ew[i]; }
        const float winv = 1.0f / wsum;
        float wid[10];
        #pragma unroll
        for (int i = 0; i < 10; ++i) wid[i] = 1.0e-3f + 0.99f * ew[i] * winv;

        float hx[11];
        #pragma unroll
        for (int i = 0; i < 11; ++i) hx[i] = __expf(p[10 + i]);
        float area = 0.f;
        #pragma unroll
        for (int i = 0; i < 10; ++i) area += (hx[i] + hx[i + 1]) * wid[i];
        const float ainv = 2.0f / area;
        float hts[11];
        #pragma unroll
        for (int i = 0; i < 11; ++i) hts[i] = 1.0e-3f + 0.999f * hx[i] * ainv;

        float la = wid[0];
        float ca = 0.5f * (hts[0] + hts[1]) * wid[0];
        float loc = 0.f, ww = wid[0], lc = 0.f, hl = hts[0], hr = hts[1];
        #pragma unroll
        for (int i = 1; i < 10; ++i) {
            const bool sel = (xv >= la);
            loc = sel ? la : loc;
            ww  = sel ? wid[i] : ww;
            lc  = sel ? ca : lc;
            hl  = sel ? hts[i] : hl;
            hr  = sel ? hts[i + 1] : hr;
            la += wid[i];
            ca += 0.5f * (hts[i] + hts[i + 1]) * wid[i];
        }
        const float al2 = (xv - loc) / ww;
        const float dh  = hr - hl;
        float y = (0.5f * dh * ww * al2 + hl * ww) * al2 + lc;
        y = fminf(fmaxf(y, 0.f), 1.f);
        out[(r0 + li) * 256 + fme] = y;
        lr += __logf(al2 * dh + hl);
    };

    #pragma unroll
    for (int ib = 0; ib < 2; ++ib) {
        const int bly = ib ? (15 - wu) : wu;
        const int nl  = (bly + 2) >> 1;          // 1..8, wave-uniform
        const int f0  = bly * 16;
        const int bly8 = bly * 8;

        #pragma unroll
        for (int pass = 0; pass < 4; ++pass) {
            const int p5  = pass * 5;
            const int fme = f0 + pass * 4 + lg;
            const float xv0 = x[(r0 + li) * 256 + fme];

            f32x4 pA[6];
            #pragma unroll
            for (int ci = 0; ci < 6; ++ci) pA[ci] = (f32x4){0.f, 0.f, 0.f, 0.f};

            f16x8 c0[6], c1[6];
            #pragma unroll
            for (int ci = 0; ci < 6; ++ci)
                c0[ci] = wh[(bly8 * 21 + p5 + ci) * 64 + lane];

            __builtin_amdgcn_s_setprio(1);
            for (int s = 0; s < nl; s += 2) {
                const int s1 = (s + 1 < nl) ? s + 1 : 0;
                #pragma unroll
                for (int ci = 0; ci < 6; ++ci)
                    c1[ci] = wh[((bly8 + s1) * 21 + p5 + ci) * 64 + lane];
                {
                    const int ko = s * 32 + lg * 8;
                    f16x8 ah = *(const f16x8*)&Ah1[li][ko];
                    f16x8 al = *(const f16x8*)&Al1[li][ko];
                    #pragma unroll
                    for (int ci = 0; ci < 6; ++ci) {
                        pA[ci] = MFMA(al, c0[ci], pA[ci]);
                        pA[ci] = MFMA(ah, c0[ci], pA[ci]);
                    }
                }
                const int s2 = (s + 2 < nl) ? s + 2 : 0;
                #pragma unroll
                for (int ci = 0; ci < 6; ++ci)
                    c0[ci] = wh[((bly8 + s2) * 21 + p5 + ci) * 64 + lane];
                if (s + 1 < nl) {
                    const int ko = s1 * 32 + lg * 8;
                    f16x8 ah = *(const f16x8*)&Ah1[li][ko];
                    f16x8 al = *(const f16x8*)&Al1[li][ko];
                    #pragma unroll
                    for (int ci = 0; ci < 6; ++ci) {
                        pA[ci] = MFMA(al, c1[ci], pA[ci]);
                        pA[ci] = MFMA(ah, c1[ci], pA[ci]);
                    }
                }
            }
            __builtin_amdgcn_s_setprio(0);

            do_half(pA, xv0, pass, f0, fme, lr0);
        }
    }

    // ---- logabsdet: reduce over feature-slots (lg), then waves ----
    lr0 += __shfl_xor(lr0, 16);
    lr0 += __shfl_xor(lr0, 32);
    if (lane < 16) ladp[wu * 16 + lane] = lr0;
    __syncthreads();
    if (t < 16) {
        float s = 0.f;
        #pragma unroll
        for (int w2 = 0; w2 < 8; ++w2) s += ladp[w2 * 16 + t];
        lad[r0 + t] = s;
    }
}

// ---------------------------------------------------------------------------
extern "C" void kernel_launch(void* const* d_in, const int* in_sizes, int n_in,
                              void* d_out, int out_size, void* d_ws, size_t ws_size,
                              hipStream_t stream)
{
    const float* x  = (const float*)d_in[0];
    const float* W0 = (const float*)d_in[1];
    const float* b0 = (const float*)d_in[2];
    const float* Wb = (const float*)d_in[3];
    const float* bb = (const float*)d_in[4];
    const float* Wf = (const float*)d_in[5];
    const float* bf = (const float*)d_in[6];

    float* out = (float*)d_out;
    float* lad = out + 8192 * 256;
    unsigned char* wsb = (unsigned char*)d_ws;

    hipFuncSetAttribute(reinterpret_cast<const void*>(mega_kernel),
                        hipFuncAttributeMaxDynamicSharedMemorySize, SMEM_BYTES);

    prep_kernel<<<416, 256, 0, stream>>>(W0, Wb, Wf, wsb);
    mega_kernel<<<512, 512, SMEM_BYTES, stream>>>(x, wsb, b0, bb, bf, out, lad);
}